// Round 4
// baseline (1736.963 us; speedup 1.0000x reference)
//
#include <hip/hip_runtime.h>
#include <cstdint>
#include <cstddef>
#include <cmath>

#define D 256
#define H 4
#define LN_EPS 1e-5f
#define SPAD 512
#define NMAT 13

typedef __attribute__((ext_vector_type(8))) short short8;
typedef __attribute__((ext_vector_type(4))) short short4v;
typedef __attribute__((ext_vector_type(4))) float f32x4;

static __device__ __forceinline__ short f2bf(float f) {
    union { float f; unsigned u; } a; a.f = f;
    unsigned r = a.u + 0x7fffu + ((a.u >> 16) & 1u);
    return (short)(r >> 16);
}

// exact int divide by small runtime divisor via float reciprocal + correction
static __device__ __forceinline__ int idivf(int x, int Kc, float rKc) {
    int q = (int)((float)x * rKc);
    q -= (q * Kc > x) ? 1 : 0;
    q += ((q + 1) * Kc <= x) ? 1 : 0;
    return q;
}

// ---------- pack fp32 W[k][n] -> bf16 Bt[n][k] ----------
struct PackArgs { const float* src[NMAT]; float scale[NMAT]; short* dst; };

__global__ __launch_bounds__(256)
void pack_kernel(PackArgs pa)
{
    const int mat = blockIdx.y;
    const int el = blockIdx.x * 256 + threadIdx.x;
    const int n = el & 255, k = el >> 8;
    pa.dst[(size_t)mat * 65536 + (size_t)n * 256 + k] =
        f2bf(pa.src[mat][(size_t)k * 256 + n] * pa.scale[mat]);
}

// ---------- fp32 -> bf16 cast ----------
__global__ __launch_bounds__(256)
void cast_kernel(const float* __restrict__ x, short* __restrict__ xb, long n)
{
    const long i = ((long)blockIdx.x * 256 + threadIdx.x) * 4;
    if (i >= n) return;
    const f32x4 v = *(const f32x4*)(x + i);
    short4v o;
    o.x = f2bf(v.x); o.y = f2bf(v.y); o.z = f2bf(v.z); o.w = f2bf(v.w);
    *(short4v*)(xb + i) = o;
}

// ---------- shared MFMA mainloop: 16 rows x 256 cols per wave, K=256 ----------
static __device__ __forceinline__ void gemm_tile(const short* __restrict__ A,
                                                 const short* __restrict__ Bt,
                                                 int rowA, int l16, int quad,
                                                 f32x4 (&acc)[16])
{
    const short* Ar = A + (size_t)rowA * D + quad * 8;
    const short* Bl = Bt + (size_t)l16 * D + quad * 8;
    #pragma unroll
    for (int nt = 0; nt < 16; ++nt) acc[nt] = (f32x4){0.f, 0.f, 0.f, 0.f};
    #pragma unroll
    for (int kc = 0; kc < 8; ++kc) {
        const short8 af = *(const short8*)(Ar + kc * 32);
        #pragma unroll
        for (int nt = 0; nt < 16; ++nt) {
            const short8 bf = *(const short8*)(Bl + (size_t)nt * 16 * D + kc * 32);
            acc[nt] = __builtin_amdgcn_mfma_f32_16x16x32_bf16(af, bf, acc[nt], 0, 0, 0);
        }
    }
}

// ---------- GEMM + bias + residual + LayerNorm, writes fp32 + bf16 ----------
__global__ __launch_bounds__(256)
void gemm_res_ln_kernel(const short* __restrict__ A, const short* __restrict__ Bt,
                        const float* __restrict__ bias, const float* __restrict__ resid,
                        const float* __restrict__ gam, const float* __restrict__ bet,
                        float* __restrict__ xout, short* __restrict__ xbout)
{
    const int tid = threadIdx.x, wave = tid >> 6, lane = tid & 63;
    const int l16 = lane & 15, quad = lane >> 4;
    const int row0 = blockIdx.x * 64 + wave * 16;
    f32x4 acc[16];
    gemm_tile(A, Bt, row0 + l16, l16, quad, acc);

    #pragma unroll
    for (int nt = 0; nt < 16; ++nt) {
        const int col = nt * 16 + l16;
        const float bl = bias[col];
        #pragma unroll
        for (int r = 0; r < 4; ++r)
            acc[nt][r] += bl + resid[(size_t)(row0 + quad * 4 + r) * D + col];
    }
    float mu[4], rstd[4];
    #pragma unroll
    for (int r = 0; r < 4; ++r) {
        float s = 0.f;
        #pragma unroll
        for (int nt = 0; nt < 16; ++nt) s += acc[nt][r];
        s += __shfl_xor(s, 1, 64); s += __shfl_xor(s, 2, 64);
        s += __shfl_xor(s, 4, 64); s += __shfl_xor(s, 8, 64);
        mu[r] = s * (1.f / D);
        float q = 0.f;
        #pragma unroll
        for (int nt = 0; nt < 16; ++nt) { const float d = acc[nt][r] - mu[r]; q = fmaf(d, d, q); }
        q += __shfl_xor(q, 1, 64); q += __shfl_xor(q, 2, 64);
        q += __shfl_xor(q, 4, 64); q += __shfl_xor(q, 8, 64);
        rstd[r] = rsqrtf(q * (1.f / D) + LN_EPS);
    }
    #pragma unroll
    for (int nt = 0; nt < 16; ++nt) {
        const int col = nt * 16 + l16;
        const float g = gam[col], be = bet[col];
        #pragma unroll
        for (int r = 0; r < 4; ++r) {
            const size_t idx = (size_t)(row0 + quad * 4 + r) * D + col;
            const float o = (acc[nt][r] - mu[r]) * rstd[r] * g + be;
            xout[idx] = o;
            xbout[idx] = f2bf(o);
        }
    }
}

// ---------- GEMM + bias + relu -> bf16 ----------
__global__ __launch_bounds__(256)
void gemm_relu_kernel(const short* __restrict__ A, const short* __restrict__ Bt,
                      const float* __restrict__ bias, short* __restrict__ hb)
{
    const int tid = threadIdx.x, wave = tid >> 6, lane = tid & 63;
    const int l16 = lane & 15, quad = lane >> 4;
    const int row0 = blockIdx.x * 64 + wave * 16;
    f32x4 acc[16];
    gemm_tile(A, Bt, row0 + l16, l16, quad, acc);
    #pragma unroll
    for (int nt = 0; nt < 16; ++nt) {
        const int col = nt * 16 + l16;
        const float bl = bias[col];
        #pragma unroll
        for (int r = 0; r < 4; ++r)
            hb[(size_t)(row0 + quad * 4 + r) * D + col] = f2bf(fmaxf(acc[nt][r] + bl, 0.f));
    }
}

// ---------- QKV: three GEMMs, writes Q,K (padded 512-row layout) + V^T ----------
__global__ __launch_bounds__(256)
void qkv_gemm_kernel(const short* __restrict__ A, const short* __restrict__ Wt,
                     short* __restrict__ Qb, short* __restrict__ Kb,
                     short* __restrict__ Vt, int S)
{
    const int tid = threadIdx.x, wave = tid >> 6, lane = tid & 63;
    const int l16 = lane & 15, quad = lane >> 4;
    const int row0 = blockIdx.x * 64 + wave * 16;
    int bb[4], ss[4];
    #pragma unroll
    for (int r = 0; r < 4; ++r) {
        const int row = row0 + quad * 4 + r;
        bb[r] = row / S; ss[r] = row - bb[r] * S;
    }
    #pragma unroll 1
    for (int m = 0; m < 3; ++m) {
        f32x4 acc[16];
        gemm_tile(A, Wt + (size_t)m * 65536, row0 + l16, l16, quad, acc);
        #pragma unroll
        for (int nt = 0; nt < 16; ++nt) {
            const int col = nt * 16 + l16, h = col >> 6, dim = col & 63;
            #pragma unroll
            for (int r = 0; r < 4; ++r) {
                const int bh = bb[r] * H + h;
                const short v = f2bf(acc[nt][r]);
                if (m == 0)      Qb[((size_t)bh * SPAD + ss[r]) * 64 + dim] = v;
                else if (m == 1) Kb[((size_t)bh * SPAD + ss[r]) * 64 + dim] = v;
                else             Vt[((size_t)bh * 64 + dim) * SPAD + ss[r]] = v;
            }
        }
    }
}

// ---------------- MFMA attention, global (non-online) softmax ----------------
// grid = dim3(8, qt, B*H/8): block linear id % 8 == blockIdx.x -> all q-tiles
// of one (b,h) land on one XCD (L2 locality). Wave w owns keys [w*128,w*128+128).
__global__ __launch_bounds__(256)
void attn_kernel(const short* __restrict__ Qb, const short* __restrict__ Kb,
                 const short* __restrict__ Vt,
                 const float* __restrict__ attn_w_l, const int* __restrict__ Kp,
                 short* __restrict__ out, int S)
{
    const int bh = blockIdx.z * 8 + blockIdx.x;
    const int b = bh >> 2, h = bh & 3;
    const int q0 = blockIdx.y << 4;
    const int tid = threadIdx.x;
    const int wave = tid >> 6, lane = tid & 63;
    const int l16 = lane & 15, quad = lane >> 4;
    const int NK = S - 1;
    const int Kc = Kp[0];
    const float rKc = 1.0f / (float)Kc;

    __shared__ float gsh[6];
    __shared__ __align__(16) float Mw[16][4];
    __shared__ __align__(16) float Lw[16][4];
    __shared__ __align__(16) short Pb[4][16][132];   // row stride 132 hw: quads on disjoint banks
    __shared__ float Of[4][16][64];

    if (tid < 6) gsh[tid] = tanhf(attn_w_l[h * 6 + tid]);

    int qg[4], qcls[4];
    #pragma unroll
    for (int r = 0; r < 4; ++r) {
        qg[r] = q0 + quad * 4 + r;
        qcls[r] = (qg[r] < NK) ? idivf(qg[r], Kc, rKc) : -1;
    }

    // Q A-fragments (padded layout: no clamp needed)
    const size_t qrow = ((size_t)bh * SPAD + q0 + l16) * 64;
    const short8 aq0 = *(const short8*)(Qb + qrow + quad * 8);
    const short8 aq1 = *(const short8*)(Qb + qrow + 32 + quad * 8);

    const int kb0 = wave * 128;
    const short* Kbh = Kb + (size_t)bh * SPAD * 64;
    const short* Vbh = Vt + (size_t)bh * 64 * SPAD;

    // ---- phase 1: all scores for this wave's 128-key span, kept in registers ----
    f32x4 sc[8];
    #pragma unroll
    for (int c = 0; c < 4; ++c) {
        const int kbase = kb0 + c * 32;
        const size_t kr = (size_t)(kbase + l16) * 64 + quad * 8;
        const short8 kb00 = *(const short8*)(Kbh + kr);
        const short8 kb01 = *(const short8*)(Kbh + kr + 32);
        const short8 kb10 = *(const short8*)(Kbh + kr + 16 * 64);
        const short8 kb11 = *(const short8*)(Kbh + kr + 16 * 64 + 32);
        f32x4 s0 = (f32x4){0.f, 0.f, 0.f, 0.f}, s1 = (f32x4){0.f, 0.f, 0.f, 0.f};
        s0 = __builtin_amdgcn_mfma_f32_16x16x32_bf16(aq0, kb00, s0, 0, 0, 0);
        s0 = __builtin_amdgcn_mfma_f32_16x16x32_bf16(aq1, kb01, s0, 0, 0, 0);
        s1 = __builtin_amdgcn_mfma_f32_16x16x32_bf16(aq0, kb10, s1, 0, 0, 0);
        s1 = __builtin_amdgcn_mfma_f32_16x16x32_bf16(aq1, kb11, s1, 0, 0, 0);
        if (kbase + 32 > S) {                 // only the boundary chunk pays masking
            const bool v0 = (kbase + l16) < S, v1 = (kbase + 16 + l16) < S;
            #pragma unroll
            for (int r = 0; r < 4; ++r) {
                s0[r] = v0 ? s0[r] : -INFINITY;
                s1[r] = v1 ? s1[r] : -INFINITY;
            }
        }
        sc[2 * c] = s0; sc[2 * c + 1] = s1;
    }

    // ---- phase 2: global row max (one reduction for the whole row) ----
    float mr[4];
    #pragma unroll
    for (int r = 0; r < 4; ++r) {
        float m = sc[0][r];
        #pragma unroll
        for (int j = 1; j < 8; ++j) m = fmaxf(m, sc[j][r]);
        m = fmaxf(m, __shfl_xor(m, 1, 64));
        m = fmaxf(m, __shfl_xor(m, 2, 64));
        m = fmaxf(m, __shfl_xor(m, 4, 64));
        m = fmaxf(m, __shfl_xor(m, 8, 64));
        mr[r] = m;
    }
    if (l16 == 0) {
        #pragma unroll
        for (int r = 0; r < 4; ++r) Mw[quad * 4 + r][wave] = mr[r];
    }
    __syncthreads();
    float mfin[4];
    #pragma unroll
    for (int r = 0; r < 4; ++r) {
        const f32x4 mv = *(const f32x4*)Mw[quad * 4 + r];
        mfin[r] = fmaxf(fmaxf(mv[0], mv[1]), fmaxf(mv[2], mv[3]));
    }

    // ---- phase 3: exp + global sum (ungated, per reference) ----
    float ls[4] = {0.f, 0.f, 0.f, 0.f};
    #pragma unroll
    for (int j = 0; j < 8; ++j) {
        #pragma unroll
        for (int r = 0; r < 4; ++r) {
            const float e = __expf(sc[j][r] - mfin[r]);
            sc[j][r] = e;
            ls[r] += e;
        }
    }
    #pragma unroll
    for (int r = 0; r < 4; ++r) {
        ls[r] += __shfl_xor(ls[r], 1, 64);
        ls[r] += __shfl_xor(ls[r], 2, 64);
        ls[r] += __shfl_xor(ls[r], 4, 64);
        ls[r] += __shfl_xor(ls[r], 8, 64);
    }
    if (l16 == 0) {
        #pragma unroll
        for (int r = 0; r < 4; ++r) Lw[quad * 4 + r][wave] = ls[r];
    }
    __syncthreads();

    const float g0 = gsh[0], g1 = gsh[1], g2 = gsh[2],
                g3 = gsh[3], g4 = gsh[4], g5 = gsh[5];

    // ---- phase 4: gate + pack P (bf16) into per-wave LDS, A-layout transform ----
    #pragma unroll
    for (int c = 0; c < 4; ++c) {
        const int key0 = kb0 + c * 32 + l16, key1 = key0 + 16;
        const int kc0 = idivf(key0, Kc, rKc), kc1 = idivf(key1, Kc, rKc);
        #pragma unroll
        for (int r = 0; r < 4; ++r) {
            float p0, p1;
            if (qg[r] < NK) {
                const float gg0 = (key0 == NK) ? g3 : ((key0 == qg[r]) ? g0 : ((kc0 == qcls[r]) ? g1 : g2));
                const float gg1 = (key1 == NK) ? g3 : ((key1 == qg[r]) ? g0 : ((kc1 == qcls[r]) ? g1 : g2));
                p0 = sc[2 * c][r] * gg0; p1 = sc[2 * c + 1][r] * gg1;
            } else {
                p0 = sc[2 * c][r] * ((key0 < NK) ? g4 : g5);
                p1 = sc[2 * c + 1][r] * ((key1 < NK) ? g4 : g5);
            }
            const int row = quad * 4 + r;
            Pb[wave][row][c * 32 + l16] = f2bf(p0);
            Pb[wave][row][c * 32 + 16 + l16] = f2bf(p1);
        }
    }

    // ---- phase 5: PV over this wave's span (same-wave LDS, no barrier) ----
    f32x4 O[4];
    #pragma unroll
    for (int dt = 0; dt < 4; ++dt) O[dt] = (f32x4){0.f, 0.f, 0.f, 0.f};
    #pragma unroll
    for (int ks = 0; ks < 4; ++ks) {
        const short8 ap = *(const short8*)(&Pb[wave][l16][ks * 32 + quad * 8]);
        #pragma unroll
        for (int dt = 0; dt < 4; ++dt) {
            const short8 vb = *(const short8*)(Vbh + (size_t)(dt * 16 + l16) * SPAD + kb0 + ks * 32 + quad * 8);
            O[dt] = __builtin_amdgcn_mfma_f32_16x16x32_bf16(ap, vb, O[dt], 0, 0, 0);
        }
    }

    // ---- phase 6: cross-wave combine (plain sum; m,l were global) ----
    #pragma unroll
    for (int r = 0; r < 4; ++r) {
        const int row = quad * 4 + r;
        #pragma unroll
        for (int dt = 0; dt < 4; ++dt) Of[wave][row][dt * 16 + l16] = O[dt][r];
    }
    __syncthreads();
    const int d = tid & 63, qhi = tid >> 6;
    #pragma unroll
    for (int i = 0; i < 4; ++i) {
        const int q = qhi * 4 + i;
        const int s = q0 + q;
        if (s >= S) continue;
        const float osum = Of[0][q][d] + Of[1][q][d] + Of[2][q][d] + Of[3][q][d];
        const f32x4 lv = *(const f32x4*)Lw[q];
        const float lq = lv[0] + lv[1] + lv[2] + lv[3];
        out[((size_t)b * S + s) * D + h * 64 + d] = f2bf(osum / lq);
    }
}

extern "C" void kernel_launch(void* const* d_in, const int* in_sizes, int n_in,
                              void* d_out, int out_size, void* d_ws, size_t ws_size,
                              hipStream_t stream)
{
    const float* samples = (const float*)d_in[0];
    const float* Wq      = (const float*)d_in[1];
    const float* Wk      = (const float*)d_in[2];
    const float* Wv      = (const float*)d_in[3];
    const float* attn_w  = (const float*)d_in[4];
    const float* fc_w    = (const float*)d_in[5];
    const float* fc_b    = (const float*)d_in[6];
    const float* mha_g   = (const float*)d_in[7];
    const float* mha_b   = (const float*)d_in[8];
    const float* w1      = (const float*)d_in[9];
    const float* b1      = (const float*)d_in[10];
    const float* w2      = (const float*)d_in[11];
    const float* b2      = (const float*)d_in[12];
    const float* dg      = (const float*)d_in[13];
    const float* db      = (const float*)d_in[14];
    const float* ow      = (const float*)d_in[15];
    const float* ob      = (const float*)d_in[16];
    const float* og      = (const float*)d_in[17];
    const float* obeta   = (const float*)d_in[18];
    const int*   Kp      = (const int*)d_in[20];

    const int Bsz = 128;
    const int S = in_sizes[0] / (Bsz * D);   // 501
    const int rows = Bsz * S;                // 64128
    const size_t n_el = (size_t)rows * D;
    const size_t n_pad = (size_t)Bsz * H * SPAD * 64;   // padded QKV buffers

    float* x   = (float*)d_out;
    short* xb  = (short*)d_ws;               // bf16 activations [rows][D]
    short* aob = xb + n_el;                  // attn out bf16; later reused as hb
    short* hb  = aob;
    short* Qb  = aob + n_el;                 // [B*H][512][64]
    short* Kb  = Qb + n_pad;                 // [B*H][512][64]
    short* Vt  = Kb + n_pad;                 // [B*H][64][512]
    short* wts = Vt + n_pad;

    PackArgs pa;
    for (int l = 0; l < 2; ++l) {
        const size_t wo = (size_t)l * 65536;
        pa.src[l*6 + 0] = Wq + wo;   pa.scale[l*6 + 0] = 0.125f;
        pa.src[l*6 + 1] = Wk + wo;   pa.scale[l*6 + 1] = 1.f;
        pa.src[l*6 + 2] = Wv + wo;   pa.scale[l*6 + 2] = 1.f;
        pa.src[l*6 + 3] = fc_w + wo; pa.scale[l*6 + 3] = 1.f;
        pa.src[l*6 + 4] = w1 + wo;   pa.scale[l*6 + 4] = 1.f;
        pa.src[l*6 + 5] = w2 + wo;   pa.scale[l*6 + 5] = 1.f;
    }
    pa.src[12] = ow; pa.scale[12] = 1.f;
    pa.dst = wts;
    pack_kernel<<<dim3(256, NMAT), 256, 0, stream>>>(pa);

    hipMemcpyAsync(x, samples, n_el * sizeof(float), hipMemcpyDeviceToDevice, stream);
    cast_kernel<<<(int)((n_el / 4 + 255) / 256), 256, 0, stream>>>(samples, xb, (long)n_el);

    const int gblocks = rows / 64;           // 1002
    const int qt = (S + 15) / 16;            // 32
    for (int l = 0; l < 2; ++l) {
        short* wl = wts + (size_t)l * 6 * 65536;
        qkv_gemm_kernel<<<gblocks, 256, 0, stream>>>(xb, wl, Qb, Kb, Vt, S);
        attn_kernel<<<dim3(8, qt, Bsz * H / 8), 256, 0, stream>>>(Qb, Kb, Vt,
                                              attn_w + (size_t)l * H * 6, Kp, aob, S);
        gemm_res_ln_kernel<<<gblocks, 256, 0, stream>>>(aob, wl + 3 * 65536,
                                              fc_b + (size_t)l * D, x,
                                              mha_g + (size_t)l * D, mha_b + (size_t)l * D,
                                              x, xb);
        gemm_relu_kernel<<<gblocks, 256, 0, stream>>>(xb, wl + 4 * 65536,
                                              b1 + (size_t)l * D, hb);
        gemm_res_ln_kernel<<<gblocks, 256, 0, stream>>>(hb, wl + 5 * 65536,
                                              b2 + (size_t)l * D, x,
                                              dg + (size_t)l * D, db + (size_t)l * D,
                                              x, xb);
    }
    gemm_res_ln_kernel<<<gblocks, 256, 0, stream>>>(xb, wts + 12 * 65536,
                                              ob, samples, og, obeta, x, xb);
}

// Round 5
// 1295.812 us; speedup vs baseline: 1.3404x; 1.3404x over previous
//
#include <hip/hip_runtime.h>
#include <cstdint>
#include <cstddef>
#include <cmath>

#define D 256
#define H 4
#define LN_EPS 1e-5f
#define SPAD 512
#define NMAT 13
#define PBS 520   // Pb row stride in shorts: 1040 B = 65*16 (aligned), 260 words

typedef __attribute__((ext_vector_type(8))) short short8;
typedef __attribute__((ext_vector_type(4))) short short4v;
typedef __attribute__((ext_vector_type(4))) float f32x4;

static __device__ __forceinline__ short f2bf(float f) {
    union { float f; unsigned u; } a; a.f = f;
    unsigned r = a.u + 0x7fffu + ((a.u >> 16) & 1u);
    return (short)(r >> 16);
}

// exact int divide by small runtime divisor via float reciprocal + correction
static __device__ __forceinline__ int idivf(int x, int Kc, float rKc) {
    int q = (int)((float)x * rKc);
    q -= (q * Kc > x) ? 1 : 0;
    q += ((q + 1) * Kc <= x) ? 1 : 0;
    return q;
}

// ---------- pack fp32 W[k][n] -> bf16 fragment-ordered B ----------
// dst short index = ((kc*16+nt)*64 + quad*16 + l16)*8 + j,
// where n = nt*16+l16, k = kc*32+quad*8+j. A wave's B-frag load for (kc,nt)
// is then ONE contiguous 1024B block at ((kc*16+nt)*64 + lane)*8.
struct PackArgs { const float* src[NMAT]; float scale[NMAT]; short* dst; };

__global__ __launch_bounds__(256)
void pack_kernel(PackArgs pa)
{
    const int mat = blockIdx.y;
    const int el = blockIdx.x * 256 + threadIdx.x;
    const int n = el & 255, k = el >> 8;
    const int nt = n >> 4, l16 = n & 15;
    const int kc = k >> 5, qd = (k >> 3) & 3, j = k & 7;
    const size_t didx = (((size_t)(kc * 16 + nt) * 64) + qd * 16 + l16) * 8 + j;
    pa.dst[(size_t)mat * 65536 + didx] =
        f2bf(pa.src[mat][(size_t)k * 256 + n] * pa.scale[mat]);
}

// ---------- fused fp32 copy + bf16 cast ----------
__global__ __launch_bounds__(256)
void copy_cast_kernel(const float* __restrict__ x, float* __restrict__ xc,
                      short* __restrict__ xb, long n)
{
    const long i = ((long)blockIdx.x * 256 + threadIdx.x) * 4;
    if (i >= n) return;
    const f32x4 v = *(const f32x4*)(x + i);
    *(f32x4*)(xc + i) = v;
    short4v o;
    o.x = f2bf(v.x); o.y = f2bf(v.y); o.z = f2bf(v.z); o.w = f2bf(v.w);
    *(short4v*)(xb + i) = o;
}

// ---------- MFMA mainloop: 16 rows x 256 cols per wave, K=256 ----------
// B is fragment-ordered (see pack_kernel): loads walk memory linearly.
static __device__ __forceinline__ void gemm_tile(const short* __restrict__ A,
                                                 const short* __restrict__ Bt,
                                                 int rowA, int lane, int quad,
                                                 f32x4 (&acc)[16])
{
    const short* Ar = A + (size_t)rowA * D + quad * 8;
    const short* Bl = Bt + (size_t)lane * 8;
    #pragma unroll
    for (int nt = 0; nt < 16; ++nt) acc[nt] = (f32x4){0.f, 0.f, 0.f, 0.f};
    #pragma unroll
    for (int kc = 0; kc < 8; ++kc) {
        const short8 af = *(const short8*)(Ar + kc * 32);
        #pragma unroll
        for (int nt = 0; nt < 16; ++nt) {
            const short8 bf = *(const short8*)(Bl + (size_t)(kc * 16 + nt) * 512);
            acc[nt] = __builtin_amdgcn_mfma_f32_16x16x32_bf16(af, bf, acc[nt], 0, 0, 0);
        }
    }
}

// ---------- GEMM + bias + residual + LayerNorm, writes fp32 + bf16 ----------
__global__ __launch_bounds__(256)
void gemm_res_ln_kernel(const short* __restrict__ A, const short* __restrict__ Bt,
                        const float* __restrict__ bias, const float* __restrict__ resid,
                        const float* __restrict__ gam, const float* __restrict__ bet,
                        float* __restrict__ xout, short* __restrict__ xbout)
{
    const int tid = threadIdx.x, wave = tid >> 6, lane = tid & 63;
    const int l16 = lane & 15, quad = lane >> 4;
    const int row0 = blockIdx.x * 64 + wave * 16;
    f32x4 acc[16];
    gemm_tile(A, Bt, row0 + l16, lane, quad, acc);

    #pragma unroll
    for (int nt = 0; nt < 16; ++nt) {
        const int col = nt * 16 + l16;
        const float bl = bias[col];
        #pragma unroll
        for (int r = 0; r < 4; ++r)
            acc[nt][r] += bl + resid[(size_t)(row0 + quad * 4 + r) * D + col];
    }
    float mu[4], rstd[4];
    #pragma unroll
    for (int r = 0; r < 4; ++r) {
        float s = 0.f;
        #pragma unroll
        for (int nt = 0; nt < 16; ++nt) s += acc[nt][r];
        s += __shfl_xor(s, 1, 64); s += __shfl_xor(s, 2, 64);
        s += __shfl_xor(s, 4, 64); s += __shfl_xor(s, 8, 64);
        mu[r] = s * (1.f / D);
        float q = 0.f;
        #pragma unroll
        for (int nt = 0; nt < 16; ++nt) { const float d = acc[nt][r] - mu[r]; q = fmaf(d, d, q); }
        q += __shfl_xor(q, 1, 64); q += __shfl_xor(q, 2, 64);
        q += __shfl_xor(q, 4, 64); q += __shfl_xor(q, 8, 64);
        rstd[r] = rsqrtf(q * (1.f / D) + LN_EPS);
    }
    #pragma unroll
    for (int nt = 0; nt < 16; ++nt) {
        const int col = nt * 16 + l16;
        const float g = gam[col], be = bet[col];
        #pragma unroll
        for (int r = 0; r < 4; ++r) {
            const size_t idx = (size_t)(row0 + quad * 4 + r) * D + col;
            const float o = (acc[nt][r] - mu[r]) * rstd[r] * g + be;
            xout[idx] = o;
            xbout[idx] = f2bf(o);
        }
    }
}

// ---------- GEMM + bias + relu -> bf16 ----------
__global__ __launch_bounds__(256)
void gemm_relu_kernel(const short* __restrict__ A, const short* __restrict__ Bt,
                      const float* __restrict__ bias, short* __restrict__ hb)
{
    const int tid = threadIdx.x, wave = tid >> 6, lane = tid & 63;
    const int l16 = lane & 15, quad = lane >> 4;
    const int row0 = blockIdx.x * 64 + wave * 16;
    f32x4 acc[16];
    gemm_tile(A, Bt, row0 + l16, lane, quad, acc);
    #pragma unroll
    for (int nt = 0; nt < 16; ++nt) {
        const int col = nt * 16 + l16;
        const float bl = bias[col];
        #pragma unroll
        for (int r = 0; r < 4; ++r)
            hb[(size_t)(row0 + quad * 4 + r) * D + col] = f2bf(fmaxf(acc[nt][r] + bl, 0.f));
    }
}

// ---------- QKV: three GEMMs, writes Q,K (padded 512-row layout) + V^T ----------
__global__ __launch_bounds__(256)
void qkv_gemm_kernel(const short* __restrict__ A, const short* __restrict__ Wt,
                     short* __restrict__ Qb, short* __restrict__ Kb,
                     short* __restrict__ Vt, int S)
{
    const int tid = threadIdx.x, wave = tid >> 6, lane = tid & 63;
    const int l16 = lane & 15, quad = lane >> 4;
    const int row0 = blockIdx.x * 64 + wave * 16;
    int bb[4], ss[4];
    #pragma unroll
    for (int r = 0; r < 4; ++r) {
        const int row = row0 + quad * 4 + r;
        bb[r] = row / S; ss[r] = row - bb[r] * S;
    }
    #pragma unroll 1
    for (int m = 0; m < 3; ++m) {
        f32x4 acc[16];
        gemm_tile(A, Wt + (size_t)m * 65536, row0 + l16, lane, quad, acc);
        #pragma unroll
        for (int nt = 0; nt < 16; ++nt) {
            const int col = nt * 16 + l16, h = col >> 6, dim = col & 63;
            #pragma unroll
            for (int r = 0; r < 4; ++r) {
                const int bh = bb[r] * H + h;
                const short v = f2bf(acc[nt][r]);
                if (m == 0)      Qb[((size_t)bh * SPAD + ss[r]) * 64 + dim] = v;
                else if (m == 1) Kb[((size_t)bh * SPAD + ss[r]) * 64 + dim] = v;
                else             Vt[((size_t)bh * 64 + dim) * SPAD + ss[r]] = v;
            }
        }
    }
}

// ---------------- MFMA attention, global softmax, d-sliced PV ----------------
// grid = dim3(8, qt, B*H/8). Wave w: QK for keys [w*128,w*128+128); after the
// P barrier, PV for d-slice [w*16,w*16+16) over ALL 512 keys (no O combine).
__global__ __launch_bounds__(256)
void attn_kernel(const short* __restrict__ Qb, const short* __restrict__ Kb,
                 const short* __restrict__ Vt,
                 const float* __restrict__ attn_w_l, const int* __restrict__ Kp,
                 short* __restrict__ out, int S)
{
    const int bh = blockIdx.z * 8 + blockIdx.x;
    const int b = bh >> 2, h = bh & 3;
    const int q0 = blockIdx.y << 4;
    const int tid = threadIdx.x;
    const int wave = tid >> 6, lane = tid & 63;
    const int l16 = lane & 15, quad = lane >> 4;
    const int NK = S - 1;
    const int Kc = Kp[0];
    const float rKc = 1.0f / (float)Kc;

    __shared__ float gsh[6];
    __shared__ __align__(16) float Mw[16][4];
    __shared__ __align__(16) float Lw[16][4];
    __shared__ __align__(16) short Pb[16][PBS];   // [q][key], 512 keys

    if (tid < 6) gsh[tid] = tanhf(attn_w_l[h * 6 + tid]);

    const size_t qrow = ((size_t)bh * SPAD + q0 + l16) * 64;
    const short8 aq0 = *(const short8*)(Qb + qrow + quad * 8);
    const short8 aq1 = *(const short8*)(Qb + qrow + 32 + quad * 8);

    const int kb0 = wave * 128;
    const short* Kbh = Kb + (size_t)bh * SPAD * 64;
    const short* Vbh = Vt + (size_t)bh * 64 * SPAD;

    // ---- phase 1: scores for this wave's 128-key span, in registers ----
    f32x4 sc[8];
    #pragma unroll
    for (int c = 0; c < 4; ++c) {
        const int kbase = kb0 + c * 32;
        const size_t kr = (size_t)(kbase + l16) * 64 + quad * 8;
        const short8 kb00 = *(const short8*)(Kbh + kr);
        const short8 kb01 = *(const short8*)(Kbh + kr + 32);
        const short8 kb10 = *(const short8*)(Kbh + kr + 16 * 64);
        const short8 kb11 = *(const short8*)(Kbh + kr + 16 * 64 + 32);
        f32x4 s0 = (f32x4){0.f, 0.f, 0.f, 0.f}, s1 = (f32x4){0.f, 0.f, 0.f, 0.f};
        s0 = __builtin_amdgcn_mfma_f32_16x16x32_bf16(aq0, kb00, s0, 0, 0, 0);
        s0 = __builtin_amdgcn_mfma_f32_16x16x32_bf16(aq1, kb01, s0, 0, 0, 0);
        s1 = __builtin_amdgcn_mfma_f32_16x16x32_bf16(aq0, kb10, s1, 0, 0, 0);
        s1 = __builtin_amdgcn_mfma_f32_16x16x32_bf16(aq1, kb11, s1, 0, 0, 0);
        if (kbase + 32 > S) {
            const bool v0 = (kbase + l16) < S, v1 = (kbase + 16 + l16) < S;
            #pragma unroll
            for (int r = 0; r < 4; ++r) {
                s0[r] = v0 ? s0[r] : -INFINITY;
                s1[r] = v1 ? s1[r] : -INFINITY;
            }
        }
        sc[2 * c] = s0; sc[2 * c + 1] = s1;
    }

    // ---- phase 2: global row max ----
    float mr[4];
    #pragma unroll
    for (int r = 0; r < 4; ++r) {
        float m = sc[0][r];
        #pragma unroll
        for (int j = 1; j < 8; ++j) m = fmaxf(m, sc[j][r]);
        m = fmaxf(m, __shfl_xor(m, 1, 64));
        m = fmaxf(m, __shfl_xor(m, 2, 64));
        m = fmaxf(m, __shfl_xor(m, 4, 64));
        m = fmaxf(m, __shfl_xor(m, 8, 64));
        mr[r] = m;
    }
    if (l16 == 0) {
        #pragma unroll
        for (int r = 0; r < 4; ++r) Mw[quad * 4 + r][wave] = mr[r];
    }
    __syncthreads();
    float mfin[4];
    #pragma unroll
    for (int r = 0; r < 4; ++r) {
        const f32x4 mv = *(const f32x4*)Mw[quad * 4 + r];
        mfin[r] = fmaxf(fmaxf(mv[0], mv[1]), fmaxf(mv[2], mv[3]));
    }

    // ---- phase 3: exp + global sum (ungated, per reference) ----
    float ls[4] = {0.f, 0.f, 0.f, 0.f};
    #pragma unroll
    for (int j = 0; j < 8; ++j) {
        #pragma unroll
        for (int r = 0; r < 4; ++r) {
            const float e = __expf(sc[j][r] - mfin[r]);
            sc[j][r] = e;
            ls[r] += e;
        }
    }
    #pragma unroll
    for (int r = 0; r < 4; ++r) {
        ls[r] += __shfl_xor(ls[r], 1, 64);
        ls[r] += __shfl_xor(ls[r], 2, 64);
        ls[r] += __shfl_xor(ls[r], 4, 64);
        ls[r] += __shfl_xor(ls[r], 8, 64);
    }
    if (l16 == 0) {
        #pragma unroll
        for (int r = 0; r < 4; ++r) Lw[quad * 4 + r][wave] = ls[r];
    }

    // ---- phase 4: branchless gate + pack P into LDS ----
    const float g0 = gsh[0], g1 = gsh[1], g2 = gsh[2],
                g3 = gsh[3], g4 = gsh[4], g5 = gsh[5];
    int qg[4]; unsigned qlo[4]; float gdef[4], gnk[4], gdia[4];
    #pragma unroll
    for (int r = 0; r < 4; ++r) {
        qg[r] = q0 + quad * 4 + r;
        const bool qs = qg[r] < NK;
        qlo[r] = qs ? (unsigned)(idivf(qg[r], Kc, rKc) * Kc) : 0x40000000u;
        gdef[r] = qs ? g2 : g4;
        gnk[r]  = qs ? g3 : g5;
        gdia[r] = qs ? g0 : g5;
    }
    #pragma unroll
    for (int c = 0; c < 4; ++c) {
        const int key0 = kb0 + c * 32 + l16, key1 = key0 + 16;
        #pragma unroll
        for (int r = 0; r < 4; ++r) {
            float gg0 = ((unsigned)(key0 - qlo[r]) < (unsigned)Kc) ? g1 : gdef[r];
            gg0 = (key0 == NK) ? gnk[r] : gg0;
            gg0 = (key0 == qg[r]) ? gdia[r] : gg0;
            float gg1 = ((unsigned)(key1 - qlo[r]) < (unsigned)Kc) ? g1 : gdef[r];
            gg1 = (key1 == NK) ? gnk[r] : gg1;
            gg1 = (key1 == qg[r]) ? gdia[r] : gg1;
            const int row = quad * 4 + r;
            Pb[row][kb0 + c * 32 + l16] = f2bf(sc[2 * c][r] * gg0);
            Pb[row][kb0 + c * 32 + 16 + l16] = f2bf(sc[2 * c + 1][r] * gg1);
        }
    }
    __syncthreads();

    // ---- phase 5: PV for this wave's d-slice over all 512 keys ----
    const int dsl = wave * 16;
    f32x4 O = (f32x4){0.f, 0.f, 0.f, 0.f};
    #pragma unroll
    for (int ks = 0; ks < 16; ++ks) {
        const short8 ap = *(const short8*)(&Pb[l16][ks * 32 + quad * 8]);
        const short8 vb = *(const short8*)(Vbh + (size_t)(dsl + l16) * SPAD + ks * 32 + quad * 8);
        O = __builtin_amdgcn_mfma_f32_16x16x32_bf16(ap, vb, O, 0, 0, 0);
    }

    // ---- epilogue: divide by global l, write bf16 ----
    #pragma unroll
    for (int r = 0; r < 4; ++r) {
        const int q = quad * 4 + r;
        const int s = q0 + q;
        if (s < S) {
            const f32x4 lv = *(const f32x4*)Lw[q];
            const float lq = lv[0] + lv[1] + lv[2] + lv[3];
            out[((size_t)b * S + s) * D + h * 64 + dsl + l16] = f2bf(O[r] / lq);
        }
    }
}

extern "C" void kernel_launch(void* const* d_in, const int* in_sizes, int n_in,
                              void* d_out, int out_size, void* d_ws, size_t ws_size,
                              hipStream_t stream)
{
    const float* samples = (const float*)d_in[0];
    const float* Wq      = (const float*)d_in[1];
    const float* Wk      = (const float*)d_in[2];
    const float* Wv      = (const float*)d_in[3];
    const float* attn_w  = (const float*)d_in[4];
    const float* fc_w    = (const float*)d_in[5];
    const float* fc_b    = (const float*)d_in[6];
    const float* mha_g   = (const float*)d_in[7];
    const float* mha_b   = (const float*)d_in[8];
    const float* w1      = (const float*)d_in[9];
    const float* b1      = (const float*)d_in[10];
    const float* w2      = (const float*)d_in[11];
    const float* b2      = (const float*)d_in[12];
    const float* dg      = (const float*)d_in[13];
    const float* db      = (const float*)d_in[14];
    const float* ow      = (const float*)d_in[15];
    const float* ob      = (const float*)d_in[16];
    const float* og      = (const float*)d_in[17];
    const float* obeta   = (const float*)d_in[18];
    const int*   Kp      = (const int*)d_in[20];

    const int Bsz = 128;
    const int S = in_sizes[0] / (Bsz * D);   // 501
    const int rows = Bsz * S;                // 64128
    const size_t n_el = (size_t)rows * D;
    const size_t n_pad = (size_t)Bsz * H * SPAD * 64;

    float* x   = (float*)d_out;
    short* xb  = (short*)d_ws;               // bf16 activations [rows][D]
    short* aob = xb + n_el;                  // attn out bf16; later reused as hb
    short* hb  = aob;
    short* Qb  = aob + n_el;                 // [B*H][512][64]
    short* Kb  = Qb + n_pad;                 // [B*H][512][64]
    short* Vt  = Kb + n_pad;                 // [B*H][64][512]
    short* wts = Vt + n_pad;

    PackArgs pa;
    for (int l = 0; l < 2; ++l) {
        const size_t wo = (size_t)l * 65536;
        pa.src[l*6 + 0] = Wq + wo;   pa.scale[l*6 + 0] = 0.125f;
        pa.src[l*6 + 1] = Wk + wo;   pa.scale[l*6 + 1] = 1.f;
        pa.src[l*6 + 2] = Wv + wo;   pa.scale[l*6 + 2] = 1.f;
        pa.src[l*6 + 3] = fc_w + wo; pa.scale[l*6 + 3] = 1.f;
        pa.src[l*6 + 4] = w1 + wo;   pa.scale[l*6 + 4] = 1.f;
        pa.src[l*6 + 5] = w2 + wo;   pa.scale[l*6 + 5] = 1.f;
    }
    pa.src[12] = ow; pa.scale[12] = 1.f;
    pa.dst = wts;
    pack_kernel<<<dim3(256, NMAT), 256, 0, stream>>>(pa);

    copy_cast_kernel<<<(int)((n_el / 4 + 255) / 256), 256, 0, stream>>>(samples, x, xb, (long)n_el);

    const int gblocks = rows / 64;           // 1002
    const int qt = (S + 15) / 16;            // 32
    for (int l = 0; l < 2; ++l) {
        short* wl = wts + (size_t)l * 6 * 65536;
        qkv_gemm_kernel<<<gblocks, 256, 0, stream>>>(xb, wl, Qb, Kb, Vt, S);
        attn_kernel<<<dim3(8, qt, Bsz * H / 8), 256, 0, stream>>>(Qb, Kb, Vt,
                                              attn_w + (size_t)l * H * 6, Kp, aob, S);
        gemm_res_ln_kernel<<<gblocks, 256, 0, stream>>>(aob, wl + 3 * 65536,
                                              fc_b + (size_t)l * D, x,
                                              mha_g + (size_t)l * D, mha_b + (size_t)l * D,
                                              x, xb);
        gemm_relu_kernel<<<gblocks, 256, 0, stream>>>(xb, wl + 4 * 65536,
                                              b1 + (size_t)l * D, hb);
        gemm_res_ln_kernel<<<gblocks, 256, 0, stream>>>(hb, wl + 5 * 65536,
                                              b2 + (size_t)l * D, x,
                                              dg + (size_t)l * D, db + (size_t)l * D,
                                              x, xb);
    }
    gemm_res_ln_kernel<<<gblocks, 256, 0, stream>>>(xb, wts + 12 * 65536,
                                              ob, samples, og, obeta, x, xb);
}